// Round 11
// baseline (318.062 us; speedup 1.0000x reference)
//
#include <hip/hip_runtime.h>
#include <hip/hip_bf16.h>

// FastBinaryLinear: y[t,o] = scale[o] * sum_i x[t,i]*sign(w[o,i])
// R11: i8 path, 128x256 tile, BK=64, 8 waves (64x64/wave, acc=64 VGPR).
// B-frags load DIRECT global->registers (double-buffered, 1-tile lead),
// LDS carries only A (8KB/tile, quad-buffered 32KB) -> LDS read traffic
// halved; 2 blocks/CU. Gate discipline: VMC then BAR, reads after BAR.

typedef int i32x4 __attribute__((ext_vector_type(4)));
typedef const __attribute__((address_space(1))) void* gptr_t;
typedef __attribute__((address_space(3))) void* lptr_t;

template<bool V> struct BoolC { static constexpr bool value = V; };

// ---- fused pre-pass: blocks [0,M) quantize x rows; [M, M+N) sign w rows ----
__global__ __launch_bounds__(256) void prep_kernel(
    const float4* __restrict__ x, const float4* __restrict__ w,
    unsigned* __restrict__ xq, unsigned* __restrict__ wq,
    float* __restrict__ alpha, int M, int N, int K) {
  const int bid = blockIdx.x;
  const int t = threadIdx.x;
  const int n4 = K >> 2;

  if (bid < M) {
    const int row = bid;
    const float4* xr = x + (size_t)row * n4;
    unsigned* qr = xq + (size_t)row * n4;

    float m = 0.f;
    for (int i = t; i < n4; i += 256) {
      float4 v = xr[i];
      m = fmaxf(m, fmaxf(fmaxf(fabsf(v.x), fabsf(v.y)), fmaxf(fabsf(v.z), fabsf(v.w))));
    }
    for (int o = 32; o > 0; o >>= 1) m = fmaxf(m, __shfl_xor(m, o));
    __shared__ float wm_[4];
    if ((t & 63) == 0) wm_[t >> 6] = m;
    __syncthreads();
    m = fmaxf(fmaxf(wm_[0], wm_[1]), fmaxf(wm_[2], wm_[3]));

    const float inv = m > 0.f ? 127.f / m : 0.f;
    if (t == 0) alpha[row] = m > 0.f ? m / 127.f : 0.f;

    for (int i = t; i < n4; i += 256) {
      float4 v = xr[i];  // cache-resident re-read
      int q0 = (int)rintf(v.x * inv), q1 = (int)rintf(v.y * inv);
      int q2 = (int)rintf(v.z * inv), q3 = (int)rintf(v.w * inv);
      qr[i] = (unsigned)(q0 & 255) | ((unsigned)(q1 & 255) << 8) |
              ((unsigned)(q2 & 255) << 16) | ((unsigned)(q3 & 255) << 24);
    }
  } else {
    const int row = bid - M;
    const float4* wr = w + (size_t)row * n4;
    unsigned* qr = wq + (size_t)row * n4;
    for (int i = t; i < n4; i += 256) {
      float4 f = wr[i];
      int s0 = (f.x > 0.f) - (f.x < 0.f);
      int s1 = (f.y > 0.f) - (f.y < 0.f);
      int s2 = (f.z > 0.f) - (f.z < 0.f);
      int s3 = (f.w > 0.f) - (f.w < 0.f);
      qr[i] = (unsigned)(s0 & 255) | ((unsigned)(s1 & 255) << 8) |
              ((unsigned)(s2 & 255) << 16) | ((unsigned)(s3 & 255) << 24);
    }
  }
}

// ---- 128x256 BK=64 i8 GEMM: A via LDS (quad-buffer), B direct to regs ----
// A LDS buffer (8 KB): 8 subtiles(16r x 64B); stored slot s holds global
// chunk s ^ ((row>>1)&3) (r8-verified swizzle); reader lane (rho,G) reads
// slot G ^ ((rho>>1)&3).  B-frag: lane (rho,ch) loads 16B at row
// n0+wn*64+nf*16+rho, k = kt*64 + ch*16 (4 lanes/row = one 64B line).
__global__ __launch_bounds__(512, 4) void gemm128_i8_kernel(
    const signed char* __restrict__ A,   // [M][K] i8 (quantized x)
    const signed char* __restrict__ B,   // [N][K] i8 (sign w)
    const float* __restrict__ scale,     // [N]
    const float* __restrict__ alpha,     // [M]
    float* __restrict__ C,               // [M][N] f32
    int M, int N, int K) {
  __shared__ __align__(16) char lds[32768];   // 4 x 8192 (A only)

  const int t = threadIdx.x;
  const int lane = t & 63;
  const int wv = t >> 6;
  const int wm = wv >> 2;   // 0..1 (64-row half of BM=128)
  const int wn = wv & 3;    // 0..3 (64-col quarter of BN=256)

  const int nbn = N >> 8;
  const int bn = blockIdx.x % nbn;
  const int bm = blockIdx.x / nbn;
  const int m0 = bm << 7, n0 = bn << 8;

  // A staging: 8KB issue = 128 rows x 64 B; thread t -> row t>>2, slot t&3
  const int rlo = t >> 2;                      // 0..127
  const int gsw = (t & 3) ^ ((t >> 3) & 3);    // inverse-swizzled chunk
  const signed char* gA = A + (size_t)(m0 + rlo) * K + gsw * 16;
  const int stBase = wv << 10;  // wave-uniform; HW adds lane*16

  // ds_read lane base (A)
  const int rho = lane & 15;
  const int gix = (lane >> 4) ^ ((rho >> 1) & 3);
  const int dsA = (wm << 12) + (rho << 6) + (gix << 4);

  // B direct-load lane base
  const signed char* gBc = B + (size_t)(n0 + wn * 64 + rho) * K + ((lane >> 4) << 4);
  const size_t bNfStride = (size_t)16 * K;

#define STAGE_A(KT)                                                           \
  __builtin_amdgcn_global_load_lds(                                           \
      (gptr_t)(gA + (size_t)(KT)*64),                                         \
      (lptr_t)(lds + (((KT) & 3) << 13) + stBase), 16, 0, 0)
#define LOADB(SET, KT)                                                        \
  _Pragma("unroll")                                                           \
  for (int nf = 0; nf < 4; nf++)                                              \
    SET[nf] = *(const i32x4*)(gBc + (size_t)nf * bNfStride + (size_t)(KT)*64)

#define RD_A(MF, KT) (*(const i32x4*)(lds + (((KT) & 3) << 13) + dsA + (MF)*1024))
#define BAR() asm volatile("s_barrier" ::: "memory")
#define VMC(N) asm volatile("s_waitcnt vmcnt(" #N ")" ::: "memory")
#define MFMA8(MF0, BSET)                                              \
  __builtin_amdgcn_s_setprio(1);                                      \
  _Pragma("unroll")                                                   \
  for (int j = 0; j < 2; j++)                                         \
    _Pragma("unroll")                                                 \
    for (int nf = 0; nf < 4; nf++)                                    \
      acc[(MF0) + j][nf] = __builtin_amdgcn_mfma_i32_16x16x64_i8(     \
          aq[j], BSET[nf], acc[(MF0) + j][nf], 0, 0, 0);              \
  __builtin_amdgcn_s_setprio(0)

  i32x4 acc[4][4];
#pragma unroll
  for (int i = 0; i < 4; i++)
#pragma unroll
    for (int j = 0; j < 4; j++) acc[i][j] = (i32x4)(0);

  i32x4 aq[2], bqX[4], bqY[4];

  // ---- prologue (ledger order matters): S(0); B4(0)->X; S(1) ----
  STAGE_A(0);
  LOADB(bqX, 0);
  STAGE_A(1);

  // Tile j: [B4(j+1)->alt; S(j+2); VMC(gate); BAR; A-reads(j); MFMA(j)]
  // steady gate: outstanding after issues = S(j+1)+B4(j+1)+S(j+2) = 6.
  // VMC before BAR => all waves' S(j) complete before any wave reads (r5
  // discipline). Quad-buffer => S(j+2) (writes buf (j+2)&3) cannot collide
  // with pending reads (only tile j-1's, buf (j-1)&3, can be in flight).
#define TILE(J, CURSET, NXTSET, GATE_HAS_B, GATE)                     \
  do {                                                                \
    if constexpr (GATE_HAS_B) { LOADB(NXTSET, (J) + 1); }             \
    if ((J) + 2 < nt_) { STAGE_A((J) + 2); }                          \
    VMC(GATE);                                                        \
    BAR();                                                            \
    aq[0] = RD_A(2, J); aq[1] = RD_A(3, J);                           \
    MFMA8(2, CURSET);                                                 \
    aq[0] = RD_A(0, J); aq[1] = RD_A(1, J);                           \
    MFMA8(0, CURSET);                                                 \
  } while (0)

  const int nt_ = K >> 6;   // #K64 tiles (even, >= 4 by guard)

  int j = 0;
  for (; j + 2 < nt_; j += 2) {
    TILE(j,     bqX, bqY, true, 6);
    TILE(j + 1, bqY, bqX, true, 6);
  }
  // last pair: tile nt-2 issues B4(nt-1) only -> gate 5; tile nt-1 -> 0.
  TILE(nt_ - 2, bqX, bqY, true, 5);
  TILE(nt_ - 1, bqY, bqX, false, 0);
#undef TILE

  // ---- epilogue: C/D col=lane&15, row=(lane>>4)*4+j; y = acc*alpha*scale ----
  const int cc = lane & 15;
  const int cr4 = (lane >> 4) << 2;
#pragma unroll
  for (int nf = 0; nf < 4; nf++) {
    const int col = n0 + wn * 64 + nf * 16 + cc;
    const float s = scale[col];
#pragma unroll
    for (int mf = 0; mf < 4; mf++) {
      const int row = m0 + wm * 64 + mf * 16 + cr4;
#pragma unroll
      for (int jj = 0; jj < 4; jj++)
        C[(size_t)(row + jj) * N + col] = (float)acc[mf][nf][jj] * (s * alpha[row + jj]);
    }
  }
#undef STAGE_A
#undef LOADB
#undef RD_A
#undef BAR
#undef VMC
#undef MFMA8
}

// ---- fallback: f32 tiled GEMM (odd shapes / tiny ws) ----
__global__ __launch_bounds__(256) void fallback_gemm_kernel(
    const float* __restrict__ x, const float* __restrict__ w,
    const float* __restrict__ scale, float* __restrict__ out,
    int M, int N, int K) {
  __shared__ float xs[16][17];
  __shared__ float ws_[16][17];
  int nb = N / 16;
  int bx = blockIdx.x % nb;
  int by = blockIdx.x / nb;
  int tx = threadIdx.x % 16;
  int ty = threadIdx.x / 16;
  float acc = 0.f;
  for (int k0 = 0; k0 < K; k0 += 16) {
    xs[ty][tx] = x[(size_t)(by * 16 + ty) * K + k0 + tx];
    float wv = w[(size_t)(bx * 16 + ty) * K + k0 + tx];
    ws_[ty][tx] = (float)((wv > 0.f) - (wv < 0.f));
    __syncthreads();
#pragma unroll
    for (int kk = 0; kk < 16; kk++) acc += xs[ty][kk] * ws_[tx][kk];
    __syncthreads();
  }
  int row = by * 16 + ty, col = bx * 16 + tx;
  out[(size_t)row * N + col] = acc * scale[col];
}

extern "C" void kernel_launch(void* const* d_in, const int* in_sizes, int n_in,
                              void* d_out, int out_size, void* d_ws, size_t ws_size,
                              hipStream_t stream) {
  const float* x = (const float*)d_in[0];
  const float* w = (const float*)d_in[1];
  const float* scale = (const float*)d_in[2];
  float* out = (float*)d_out;

  const int N = in_sizes[2];
  const int K = in_sizes[1] / N;
  const int M = in_sizes[0] / K;

  const size_t xq_bytes = (size_t)M * K;
  const size_t wq_bytes = (size_t)N * K;
  const size_t al_bytes = (size_t)M * 4;
  const bool shapes_ok = (M % 128 == 0) && (N % 256 == 0) && (K % 128 == 0) && (K >= 256);

  if (shapes_ok && ws_size >= xq_bytes + wq_bytes + al_bytes) {
    signed char* xq = (signed char*)d_ws;
    signed char* wq = (signed char*)((char*)d_ws + xq_bytes);
    float* alpha = (float*)((char*)d_ws + xq_bytes + wq_bytes);

    prep_kernel<<<M + N, 256, 0, stream>>>((const float4*)x, (const float4*)w,
                                           (unsigned*)xq, (unsigned*)wq, alpha, M, N, K);

    int grid = (M / 128) * (N / 256);
    gemm128_i8_kernel<<<grid, 512, 0, stream>>>(xq, wq, scale, alpha, out, M, N, K);
  } else {
    int grid = (M / 16) * (N / 16);
    fallback_gemm_kernel<<<grid, 256, 0, stream>>>(x, w, scale, out, M, N, K);
  }
}

// Round 12
// 202.833 us; speedup vs baseline: 1.5681x; 1.5681x over previous
//
#include <hip/hip_runtime.h>
#include <hip/hip_bf16.h>

// FastBinaryLinear: y[t,o] = scale[o] * sum_i x[t,i]*sign(w[o,i])
// R12: i8 path, producer-consumer WAVE SPECIALIZATION. 128x256 tile,
// BK=64, 8 waves: G0 (wv<4) accumulates even K-tiles, G1 odd. Each phase
// one group MFMAs (frags read last phase) while the other reads next-tile
// frags -> LDS pipe overlaps matrix pipe. 4x24KB LDS buffers, r10-verified
// swizzle. Final i32 LDS reduction G1->G0, G0 writes C.

typedef int i32x4 __attribute__((ext_vector_type(4)));
typedef const __attribute__((address_space(1))) void* gptr_t;
typedef __attribute__((address_space(3))) void* lptr_t;

// ---- fused pre-pass: blocks [0,M) quantize x rows; [M, M+N) sign w rows ----
__global__ __launch_bounds__(256) void prep_kernel(
    const float4* __restrict__ x, const float4* __restrict__ w,
    unsigned* __restrict__ xq, unsigned* __restrict__ wq,
    float* __restrict__ alpha, int M, int N, int K) {
  const int bid = blockIdx.x;
  const int t = threadIdx.x;
  const int n4 = K >> 2;

  if (bid < M) {
    const int row = bid;
    const float4* xr = x + (size_t)row * n4;
    unsigned* qr = xq + (size_t)row * n4;

    float m = 0.f;
    for (int i = t; i < n4; i += 256) {
      float4 v = xr[i];
      m = fmaxf(m, fmaxf(fmaxf(fabsf(v.x), fabsf(v.y)), fmaxf(fabsf(v.z), fabsf(v.w))));
    }
    for (int o = 32; o > 0; o >>= 1) m = fmaxf(m, __shfl_xor(m, o));
    __shared__ float wm_[4];
    if ((t & 63) == 0) wm_[t >> 6] = m;
    __syncthreads();
    m = fmaxf(fmaxf(wm_[0], wm_[1]), fmaxf(wm_[2], wm_[3]));

    const float inv = m > 0.f ? 127.f / m : 0.f;
    if (t == 0) alpha[row] = m > 0.f ? m / 127.f : 0.f;

    for (int i = t; i < n4; i += 256) {
      float4 v = xr[i];  // cache-resident re-read
      int q0 = (int)rintf(v.x * inv), q1 = (int)rintf(v.y * inv);
      int q2 = (int)rintf(v.z * inv), q3 = (int)rintf(v.w * inv);
      qr[i] = (unsigned)(q0 & 255) | ((unsigned)(q1 & 255) << 8) |
              ((unsigned)(q2 & 255) << 16) | ((unsigned)(q3 & 255) << 24);
    }
  } else {
    const int row = bid - M;
    const float4* wr = w + (size_t)row * n4;
    unsigned* qr = wq + (size_t)row * n4;
    for (int i = t; i < n4; i += 256) {
      float4 f = wr[i];
      int s0 = (f.x > 0.f) - (f.x < 0.f);
      int s1 = (f.y > 0.f) - (f.y < 0.f);
      int s2 = (f.z > 0.f) - (f.z < 0.f);
      int s3 = (f.w > 0.f) - (f.w < 0.f);
      qr[i] = (unsigned)(s0 & 255) | ((unsigned)(s1 & 255) << 8) |
              ((unsigned)(s2 & 255) << 16) | ((unsigned)(s3 & 255) << 24);
    }
  }
}

// ---- 128x256 BK=64 i8 GEMM, wave-specialized ----
// Buffer (24KB): A 128rx64B @0 (8 subtiles 16rx64B), B 256rx64B @8192
// (16 subtiles). Stored slot s holds global chunk s^((row>>1)&3); staging
// thread t (row t>>2, slot t&3) fetches chunk (t&3)^((t>>3)&3); reader
// lane (rho,G) reads slot G^((rho>>1)&3).  [r10-verified geometry]
__global__ __launch_bounds__(512, 2) void gemm_ws_i8_kernel(
    const signed char* __restrict__ A,   // [M][K] i8 (quantized x)
    const signed char* __restrict__ B,   // [N][K] i8 (sign w)
    const float* __restrict__ scale,     // [N]
    const float* __restrict__ alpha,     // [M]
    float* __restrict__ C,               // [M][N] f32
    int M, int N, int K) {
  __shared__ __align__(16) char lds[98304];   // 4 x 24576

  const int t = threadIdx.x;
  const int lane = t & 63;
  const int wv = t >> 6;
  const bool isG0 = wv < 4;
  const int gw = wv & 3;     // pair id
  const int wm = gw >> 1;    // 0..1: 64-row half
  const int wn2 = gw & 1;    // 0..1: 128-col half

  const int nbn = N >> 8;
  const int bn = blockIdx.x % nbn;
  const int bm = blockIdx.x / nbn;
  const int m0 = bm << 7, n0 = bn << 8;

  // staging: 8KB issue = 128 rows x 64B over all 512 threads
  const int rlo = t >> 2;
  const int gsw = (t & 3) ^ ((t >> 3) & 3);
  const signed char* gA = A + (size_t)(m0 + rlo) * K + gsw * 16;
  const signed char* gB = B + (size_t)(n0 + rlo) * K + gsw * 16;
  const int stBase = wv << 10;  // wave-uniform; HW adds lane*16

  // read bases
  const int rho = lane & 15;
  const int gix = (lane >> 4) ^ ((rho >> 1) & 3);
  const int dsA = (wm << 12) + (rho << 6) + (gix << 4);            // +mf*1024
  const int dsB = 8192 + (wn2 << 13) + (rho << 6) + (gix << 4);    // +nf*1024

#define BUFO(J) (((J) & 3) * 24576)
#define STAGE_T(KT)                                                           \
  do {                                                                        \
    __builtin_amdgcn_global_load_lds((gptr_t)(gA + (size_t)(KT)*64),          \
        (lptr_t)(lds + BUFO(KT) + stBase), 16, 0, 0);                         \
    __builtin_amdgcn_global_load_lds((gptr_t)(gB + (size_t)(KT)*64),          \
        (lptr_t)(lds + BUFO(KT) + 8192 + stBase), 16, 0, 0);                  \
    __builtin_amdgcn_global_load_lds(                                         \
        (gptr_t)(gB + (size_t)128 * K + (size_t)(KT)*64),                     \
        (lptr_t)(lds + BUFO(KT) + 16384 + stBase), 16, 0, 0);                 \
  } while (0)

#define BAR() asm volatile("s_barrier" ::: "memory")
#define VMC(NN) asm volatile("s_waitcnt vmcnt(" #NN ")" ::: "memory")
#define LGKM0() asm volatile("s_waitcnt lgkmcnt(0)" ::: "memory")

#define READ_FRAGS(J)                                                 \
  do {                                                                \
    const char* bp_ = lds + BUFO(J);                                  \
    _Pragma("unroll")                                                 \
    for (int mf = 0; mf < 4; mf++)                                    \
      aq[mf] = *(const i32x4*)(bp_ + dsA + mf * 1024);                \
    _Pragma("unroll")                                                 \
    for (int nf = 0; nf < 8; nf++)                                    \
      bq[nf] = *(const i32x4*)(bp_ + dsB + nf * 1024);                \
  } while (0)

#define MFMA32()                                                      \
  do {                                                                \
    __builtin_amdgcn_s_setprio(1);                                    \
    _Pragma("unroll")                                                 \
    for (int mf = 0; mf < 4; mf++)                                    \
      _Pragma("unroll")                                               \
      for (int nf = 0; nf < 8; nf++)                                  \
        acc[mf][nf] = __builtin_amdgcn_mfma_i32_16x16x64_i8(          \
            aq[mf], bq[nf], acc[mf][nf], 0, 0, 0);                    \
    __builtin_amdgcn_s_setprio(0);                                    \
  } while (0)

  i32x4 acc[4][8];
#pragma unroll
  for (int i = 0; i < 4; i++)
#pragma unroll
    for (int j = 0; j < 8; j++) acc[i][j] = (i32x4)(0);

  i32x4 aq[4], bq[8];

  const int nt = K >> 6;   // even (K%128==0), >= 8

  // ---- prologue: stage T0,T1,T2; T0,T1 landed; G0 pre-reads T0 ----
  STAGE_T(0); STAGE_T(1); STAGE_T(2);
  VMC(3);
  BAR();
  if (isG0) READ_FRAGS(0);

  // Phase p: group (p even -> G0, odd -> G1) MFMAs tile p with frags read
  // at p-1; other group reads tile p+1; all stage T(p+3); gate VMC(3)
  // (=> T(p+2) landed for next phase's reads); LGKM0 (WAR: frag reads
  // drained before buf reuse 2 phases later); BAR.
  auto phase = [&](int p, bool g0turn) {
    if (isG0 == g0turn) {
      MFMA32();
    } else if (p + 1 < nt) {
      READ_FRAGS(p + 1);
    }
    if (p + 3 < nt) { STAGE_T(p + 3); VMC(3); }
    else            { VMC(0); }
    LGKM0();
    BAR();
  };

  for (int p = 0; p < nt; p += 2) {
    phase(p, true);
    phase(p + 1, false);
  }

  // ---- reduction: acc_G0 += acc_G1 via LDS (2 rounds of 64KB) ----
#pragma unroll
  for (int r = 0; r < 2; ++r) {
    if (!isG0) {
#pragma unroll
      for (int idx = 0; idx < 2; ++idx)
#pragma unroll
        for (int nf = 0; nf < 8; ++nf)
          *(i32x4*)(lds + gw * 16384 + idx * 8192 + nf * 1024 + lane * 16) =
              acc[2 * r + idx][nf];
    }
    LGKM0(); BAR();
    if (isG0) {
#pragma unroll
      for (int idx = 0; idx < 2; ++idx)
#pragma unroll
        for (int nf = 0; nf < 8; ++nf) {
          i32x4 v = *(const i32x4*)(lds + gw * 16384 + idx * 8192 + nf * 1024 + lane * 16);
          acc[2 * r + idx][nf] += v;
        }
    }
    LGKM0(); BAR();
  }

  // ---- epilogue (G0 only): C/D col=lane&15, row=(lane>>4)*4+j ----
  if (isG0) {
    const int cc = lane & 15;
    const int cr4 = (lane >> 4) << 2;
#pragma unroll
    for (int nf = 0; nf < 8; nf++) {
      const int col = n0 + wn2 * 128 + nf * 16 + cc;
      const float s = scale[col];
#pragma unroll
      for (int mf = 0; mf < 4; mf++) {
        const int row = m0 + wm * 64 + mf * 16 + cr4;
#pragma unroll
        for (int jj = 0; jj < 4; jj++)
          C[(size_t)(row + jj) * N + col] = (float)acc[mf][nf][jj] * (s * alpha[row + jj]);
      }
    }
  }
#undef BUFO
#undef STAGE_T
#undef BAR
#undef VMC
#undef LGKM0
#undef READ_FRAGS
#undef MFMA32
}

// ---- fallback: f32 tiled GEMM (odd shapes / tiny ws) ----
__global__ __launch_bounds__(256) void fallback_gemm_kernel(
    const float* __restrict__ x, const float* __restrict__ w,
    const float* __restrict__ scale, float* __restrict__ out,
    int M, int N, int K) {
  __shared__ float xs[16][17];
  __shared__ float ws_[16][17];
  int nb = N / 16;
  int bx = blockIdx.x % nb;
  int by = blockIdx.x / nb;
  int tx = threadIdx.x % 16;
  int ty = threadIdx.x / 16;
  float acc = 0.f;
  for (int k0 = 0; k0 < K; k0 += 16) {
    xs[ty][tx] = x[(size_t)(by * 16 + ty) * K + k0 + tx];
    float wv = w[(size_t)(bx * 16 + ty) * K + k0 + tx];
    ws_[ty][tx] = (float)((wv > 0.f) - (wv < 0.f));
    __syncthreads();
#pragma unroll
    for (int kk = 0; kk < 16; kk++) acc += xs[ty][kk] * ws_[tx][kk];
    __syncthreads();
  }
  int row = by * 16 + ty, col = bx * 16 + tx;
  out[(size_t)row * N + col] = acc * scale[col];
}

extern "C" void kernel_launch(void* const* d_in, const int* in_sizes, int n_in,
                              void* d_out, int out_size, void* d_ws, size_t ws_size,
                              hipStream_t stream) {
  const float* x = (const float*)d_in[0];
  const float* w = (const float*)d_in[1];
  const float* scale = (const float*)d_in[2];
  float* out = (float*)d_out;

  const int N = in_sizes[2];
  const int K = in_sizes[1] / N;
  const int M = in_sizes[0] / K;

  const size_t xq_bytes = (size_t)M * K;
  const size_t wq_bytes = (size_t)N * K;
  const size_t al_bytes = (size_t)M * 4;
  const bool shapes_ok = (M % 128 == 0) && (N % 256 == 0) && (K % 128 == 0) && (K >= 512);

  if (shapes_ok && ws_size >= xq_bytes + wq_bytes + al_bytes) {
    signed char* xq = (signed char*)d_ws;
    signed char* wq = (signed char*)((char*)d_ws + xq_bytes);
    float* alpha = (float*)((char*)d_ws + xq_bytes + wq_bytes);

    prep_kernel<<<M + N, 256, 0, stream>>>((const float4*)x, (const float4*)w,
                                           (unsigned*)xq, (unsigned*)wq, alpha, M, N, K);

    int grid = (M / 128) * (N / 256);
    gemm_ws_i8_kernel<<<grid, 512, 0, stream>>>(xq, wq, scale, alpha, out, M, N, K);
  } else {
    int grid = (M / 16) * (N / 16);
    fallback_gemm_kernel<<<grid, 256, 0, stream>>>(x, w, scale, out, M, N, K);
  }
}